// Round 1
// baseline (1757.780 us; speedup 1.0000x reference)
//
#include <hip/hip_runtime.h>
#include <hip/hip_bf16.h>

#define D 128  // D_IN == D_OUT == 128

// ---------------------------------------------------------------------------
// k0: deg[i] = 1  (self loop)
__global__ __launch_bounds__(256) void k_init_deg(int* __restrict__ deg, int n) {
    for (int i = blockIdx.x * blockDim.x + threadIdx.x; i < n; i += gridDim.x * blockDim.x)
        deg[i] = 1;
}

// k1: deg[row[e]] += 1
__global__ __launch_bounds__(256) void k_count(const int* __restrict__ rows, int* __restrict__ deg, int E) {
    for (int e = blockIdx.x * blockDim.x + threadIdx.x; e < E; e += gridDim.x * blockDim.x)
        atomicAdd(&deg[rows[e]], 1);
}

// k2a: dr[i] = rsqrt(deg[i])   (in-place int -> float reinterpret)
__global__ __launch_bounds__(256) void k_rsqrt(float* __restrict__ buf, int n) {
    const int* di = (const int*)buf;
    for (int i = blockIdx.x * blockDim.x + threadIdx.x; i < n; i += gridDim.x * blockDim.x) {
        int v = di[i];
        buf[i] = rsqrtf((float)v);
    }
}

// k2b: out[i][:] = x[i][:] * dr[i]^2   (self-loop contribution; also zeroes/initializes out)
__global__ __launch_bounds__(256) void k_init_out(const float4* __restrict__ x4,
                                                  const float* __restrict__ dr,
                                                  float4* __restrict__ out4, int n4) {
    for (int i = blockIdx.x * blockDim.x + threadIdx.x; i < n4; i += gridDim.x * blockDim.x) {
        float d = dr[i >> 5];   // 32 float4 per row
        float s = d * d;
        float4 v = x4[i];
        out4[i] = make_float4(v.x * s, v.y * s, v.z * s, v.w * s);
    }
}

// k3: edge scatter: out[row] += dr[row]*dr[col] * x[col]
// one wave (64 lanes) per edge; lane covers 2 consecutive floats of the 128-wide row
__global__ __launch_bounds__(256) void k_edges(const int* __restrict__ rows,
                                               const int* __restrict__ cols,
                                               const float* __restrict__ x,
                                               const float* __restrict__ dr,
                                               float* __restrict__ out, int E) {
    int lane = threadIdx.x & 63;
    int wib  = threadIdx.x >> 6;                  // wave in block (0..3)
    int gw   = blockIdx.x * 4 + wib;              // global wave id
    int nw   = gridDim.x * 4;
    for (int e = gw; e < E; e += nw) {
        int r = rows[e];
        int c = cols[e];
        float val = dr[r] * dr[c];
        const float2 xv = *(const float2*)&x[(size_t)c * D + lane * 2];
        float* po = &out[(size_t)r * D + lane * 2];
        unsafeAtomicAdd(po,     val * xv.x);
        unsafeAtomicAdd(po + 1, val * xv.y);
    }
}

// k4: in-place projection + relu:  out_row = relu(agg_row @ W^T)
// W^T staged in LDS (64 KB). One wave per row; lanes own 2 consecutive output cols.
__global__ __launch_bounds__(256) void k_project(const float* __restrict__ W,
                                                 float* __restrict__ out, int N) {
    __shared__ float Wt[D * D];   // Wt[k*128 + o] = W[o*128 + k]   (65536 B)
    for (int idx = threadIdx.x; idx < D * D; idx += 256) {
        int o = idx >> 7, k = idx & 127;
        Wt[k * D + o] = W[idx];
    }
    __syncthreads();

    int lane = threadIdx.x & 63;
    int wib  = threadIdx.x >> 6;
    int gw   = blockIdx.x * 4 + wib;
    int nw   = gridDim.x * 4;
    for (int r = gw; r < N; r += nw) {
        float* prow = &out[(size_t)r * D];
        float2 a = *(const float2*)&prow[lane * 2];   // a[2*lane], a[2*lane+1]
        float acc0 = 0.f, acc1 = 0.f;
#pragma unroll
        for (int kk = 0; kk < 64; ++kk) {
            float ax = __shfl(a.x, kk);               // a[2*kk]
            float ay = __shfl(a.y, kk);               // a[2*kk+1]
            float2 w0 = *(const float2*)&Wt[(2 * kk)     * D + lane * 2];
            float2 w1 = *(const float2*)&Wt[(2 * kk + 1) * D + lane * 2];
            acc0 += ax * w0.x + ay * w1.x;
            acc1 += ax * w0.y + ay * w1.y;
        }
        prow[lane * 2]     = fmaxf(acc0, 0.f);
        prow[lane * 2 + 1] = fmaxf(acc1, 0.f);
    }
}

// ---------------------------------------------------------------------------
extern "C" void kernel_launch(void* const* d_in, const int* in_sizes, int n_in,
                              void* d_out, int out_size, void* d_ws, size_t ws_size,
                              hipStream_t stream) {
    const float* x   = (const float*)d_in[0];
    const int*   idx = (const int*)d_in[1];
    const float* W   = (const float*)d_in[2];
    float*       out = (float*)d_out;

    int N = in_sizes[0] / D;        // 100000
    int E = in_sizes[1] / 2;        // 1.6M
    const int* rows = idx;
    const int* cols = idx + E;

    int*   deg = (int*)d_ws;        // N ints, reused in-place as float dr
    float* dr  = (float*)d_ws;

    k_init_deg<<<(N + 255) / 256, 256, 0, stream>>>(deg, N);
    k_count<<<2048, 256, 0, stream>>>(rows, deg, E);
    k_rsqrt<<<(N + 255) / 256, 256, 0, stream>>>(dr, N);

    int n4 = N * (D / 4);
    k_init_out<<<4096, 256, 0, stream>>>((const float4*)x, dr, (float4*)out, n4);

    k_edges<<<4096, 256, 0, stream>>>(rows, cols, x, dr, out, E);

    k_project<<<2048, 256, 0, stream>>>(W, out, N);
}

// Round 2
// 752.963 us; speedup vs baseline: 2.3345x; 2.3345x over previous
//
#include <hip/hip_runtime.h>
#include <hip/hip_bf16.h>

#define D 128  // D_IN == D_OUT == 128

// ===========================================================================
// CSR-build kernels
// ===========================================================================

// cnt[i] = 0
__global__ __launch_bounds__(256) void k_zero(int* __restrict__ cnt, int n) {
    for (int i = blockIdx.x * blockDim.x + threadIdx.x; i < n; i += gridDim.x * blockDim.x)
        cnt[i] = 0;
}

// cnt[rows[e]] += 1   (int atomics, deterministic)
__global__ __launch_bounds__(256) void k_count_csr(const int* __restrict__ rows,
                                                   int* __restrict__ cnt, int E) {
    for (int e = blockIdx.x * blockDim.x + threadIdx.x; e < E; e += gridDim.x * blockDim.x)
        atomicAdd(&cnt[rows[e]], 1);
}

// per-1024-chunk sums
__global__ __launch_bounds__(256) void k_chunk_sum(const int* __restrict__ cnt,
                                                   int* __restrict__ bsum, int N) {
    __shared__ int sd[256];
    int base = blockIdx.x * 1024;
    int t = threadIdx.x;
    int s = 0;
#pragma unroll
    for (int k = 0; k < 4; ++k) {
        int i = base + t * 4 + k;
        if (i < N) s += cnt[i];
    }
    sd[t] = s;
    __syncthreads();
    for (int off = 128; off > 0; off >>= 1) {
        if (t < off) sd[t] += sd[t + off];
        __syncthreads();
    }
    if (t == 0) bsum[blockIdx.x] = sd[0];
}

// exclusive scan of chunk sums (nb <= 1024); also writes row_start[N] = E
__global__ __launch_bounds__(1024) void k_scan_tops(const int* __restrict__ bsum,
                                                    int* __restrict__ boff, int nb,
                                                    int* __restrict__ row_start, int N, int E) {
    __shared__ int sd[1024];
    int t = threadIdx.x;
    int own = (t < nb) ? bsum[t] : 0;
    sd[t] = own;
    __syncthreads();
    for (int off = 1; off < 1024; off <<= 1) {
        int add = (t >= off) ? sd[t - off] : 0;
        __syncthreads();
        sd[t] += add;
        __syncthreads();
    }
    if (t < nb) boff[t] = sd[t] - own;  // exclusive
    if (t == 0) row_start[N] = E;
}

// per-chunk exclusive scan + boff; writes row_start, cursor, dr = rsqrt(cnt+1)
__global__ __launch_bounds__(256) void k_scan_chunk(const int* __restrict__ cnt,
                                                    const int* __restrict__ boff,
                                                    int* __restrict__ row_start,
                                                    int* __restrict__ cursor,
                                                    float* __restrict__ dr, int N) {
    __shared__ int tsum[256];
    int base = blockIdx.x * 1024;
    int t = threadIdx.x;
    int v[4];
    int s = 0;
#pragma unroll
    for (int k = 0; k < 4; ++k) {
        int i = base + t * 4 + k;
        v[k] = (i < N) ? cnt[i] : 0;
        s += v[k];
    }
    tsum[t] = s;
    __syncthreads();
    for (int off = 1; off < 256; off <<= 1) {
        int add = (t >= off) ? tsum[t - off] : 0;
        __syncthreads();
        tsum[t] += add;
        __syncthreads();
    }
    int run = boff[blockIdx.x] + tsum[t] - s;  // exclusive prefix for this thread's 4
#pragma unroll
    for (int k = 0; k < 4; ++k) {
        int i = base + t * 4 + k;
        if (i < N) {
            row_start[i] = run;
            cursor[i]    = run;
            dr[i]        = rsqrtf((float)(v[k] + 1));
            run += v[k];
        }
    }
}

// scatter col indices into CSR slots (int atomics on cursors)
__global__ __launch_bounds__(256) void k_scatter(const int* __restrict__ rows,
                                                 const int* __restrict__ cols,
                                                 int* __restrict__ cursor,
                                                 int* __restrict__ csr_col, int E) {
    for (int e = blockIdx.x * blockDim.x + threadIdx.x; e < E; e += gridDim.x * blockDim.x) {
        int p = atomicAdd(&cursor[rows[e]], 1);
        csr_col[p] = cols[e];
    }
}

// ===========================================================================
// gather: out[r] = dr[r]^2 * x[r] + sum_{c in adj(r)} dr[r]*dr[c] * x[c]
// one wave per row; lane covers 2 consecutive floats
// ===========================================================================
__global__ __launch_bounds__(256) void k_gather(const int* __restrict__ row_start,
                                                const int* __restrict__ csr_col,
                                                const float* __restrict__ x,
                                                const float* __restrict__ dr,
                                                float* __restrict__ out, int N) {
    int lane = threadIdx.x & 63;
    int gw = (blockIdx.x * blockDim.x + threadIdx.x) >> 6;
    int nw = (gridDim.x * blockDim.x) >> 6;
    for (int r = gw; r < N; r += nw) {
        float drr = dr[r];
        int beg = row_start[r], end = row_start[r + 1];
        const float2 xs = *(const float2*)&x[(size_t)r * D + lane * 2];
        float s = drr * drr;
        float a0 = s * xs.x, a1 = s * xs.y;
        for (int j = beg; j < end; ++j) {
            int c = csr_col[j];
            float val = drr * dr[c];
            const float2 xv = *(const float2*)&x[(size_t)c * D + lane * 2];
            a0 += val * xv.x;
            a1 += val * xv.y;
        }
        float2 o;
        o.x = a0;
        o.y = a1;
        *(float2*)&out[(size_t)r * D + lane * 2] = o;
    }
}

// ===========================================================================
// projection + relu, in place:  out_row = relu(agg_row @ W^T)
// ===========================================================================
__global__ __launch_bounds__(256) void k_project(const float* __restrict__ W,
                                                 float* __restrict__ out, int N) {
    __shared__ float Wt[D * D];  // Wt[k*128 + o] = W[o*128 + k]
    for (int idx = threadIdx.x; idx < D * D; idx += 256) {
        int o = idx >> 7, k = idx & 127;
        Wt[k * D + o] = W[idx];
    }
    __syncthreads();

    int lane = threadIdx.x & 63;
    int wib  = threadIdx.x >> 6;
    int gw   = blockIdx.x * 4 + wib;
    int nw   = gridDim.x * 4;
    for (int r = gw; r < N; r += nw) {
        float* prow = &out[(size_t)r * D];
        float2 a = *(const float2*)&prow[lane * 2];
        float acc0 = 0.f, acc1 = 0.f;
#pragma unroll
        for (int kk = 0; kk < 64; ++kk) {
            float ax = __shfl(a.x, kk);
            float ay = __shfl(a.y, kk);
            float2 w0 = *(const float2*)&Wt[(2 * kk) * D + lane * 2];
            float2 w1 = *(const float2*)&Wt[(2 * kk + 1) * D + lane * 2];
            acc0 += ax * w0.x + ay * w1.x;
            acc1 += ax * w0.y + ay * w1.y;
        }
        prow[lane * 2]     = fmaxf(acc0, 0.f);
        prow[lane * 2 + 1] = fmaxf(acc1, 0.f);
    }
}

// ===========================================================================
// fallback (round-1 atomic path) kernels, used only if ws too small
// ===========================================================================
__global__ __launch_bounds__(256) void k_init_deg(int* __restrict__ deg, int n) {
    for (int i = blockIdx.x * blockDim.x + threadIdx.x; i < n; i += gridDim.x * blockDim.x)
        deg[i] = 1;
}
__global__ __launch_bounds__(256) void k_rsqrt(float* __restrict__ buf, int n) {
    const int* di = (const int*)buf;
    for (int i = blockIdx.x * blockDim.x + threadIdx.x; i < n; i += gridDim.x * blockDim.x) {
        int v = di[i];
        buf[i] = rsqrtf((float)v);
    }
}
__global__ __launch_bounds__(256) void k_init_out(const float4* __restrict__ x4,
                                                  const float* __restrict__ dr,
                                                  float4* __restrict__ out4, int n4) {
    for (int i = blockIdx.x * blockDim.x + threadIdx.x; i < n4; i += gridDim.x * blockDim.x) {
        float d = dr[i >> 5];
        float s = d * d;
        float4 v = x4[i];
        out4[i] = make_float4(v.x * s, v.y * s, v.z * s, v.w * s);
    }
}
__global__ __launch_bounds__(256) void k_edges(const int* __restrict__ rows,
                                               const int* __restrict__ cols,
                                               const float* __restrict__ x,
                                               const float* __restrict__ dr,
                                               float* __restrict__ out, int E) {
    int lane = threadIdx.x & 63;
    int wib  = threadIdx.x >> 6;
    int gw   = blockIdx.x * 4 + wib;
    int nw   = gridDim.x * 4;
    for (int e = gw; e < E; e += nw) {
        int r = rows[e];
        int c = cols[e];
        float val = dr[r] * dr[c];
        const float2 xv = *(const float2*)&x[(size_t)c * D + lane * 2];
        float* po = &out[(size_t)r * D + lane * 2];
        unsafeAtomicAdd(po,     val * xv.x);
        unsafeAtomicAdd(po + 1, val * xv.y);
    }
}

// ===========================================================================
extern "C" void kernel_launch(void* const* d_in, const int* in_sizes, int n_in,
                              void* d_out, int out_size, void* d_ws, size_t ws_size,
                              hipStream_t stream) {
    const float* x   = (const float*)d_in[0];
    const int*   idx = (const int*)d_in[1];
    const float* W   = (const float*)d_in[2];
    float*       out = (float*)d_out;

    int N = in_sizes[0] / D;   // 100000
    int E = in_sizes[1] / 2;   // 1.6M
    const int* rows = idx;
    const int* cols = idx + E;

    int nb = (N + 1023) / 1024;  // chunks for the scan (98)

    // workspace layout (ints unless noted)
    //   cnt[N] | row_start[N+1] | cursor[N] | dr[N] (float) | bsum[nb] | boff[nb] | csr_col[E]
    size_t need = (size_t)(4 * (size_t)N + 1 + 2 * (size_t)nb + (size_t)E) * sizeof(int);

    if (ws_size >= need && nb <= 1024) {
        int*   cnt       = (int*)d_ws;
        int*   row_start = cnt + N;
        int*   cursor    = row_start + (N + 1);
        float* dr        = (float*)(cursor + N);
        int*   bsum      = (int*)(dr + N);
        int*   boff      = bsum + nb;
        int*   csr_col   = boff + nb;

        k_zero<<<(N + 255) / 256, 256, 0, stream>>>(cnt, N);
        k_count_csr<<<2048, 256, 0, stream>>>(rows, cnt, E);
        k_chunk_sum<<<nb, 256, 0, stream>>>(cnt, bsum, N);
        k_scan_tops<<<1, 1024, 0, stream>>>(bsum, boff, nb, row_start, N, E);
        k_scan_chunk<<<nb, 256, 0, stream>>>(cnt, boff, row_start, cursor, dr, N);
        k_scatter<<<2048, 256, 0, stream>>>(rows, cols, cursor, csr_col, E);

        k_gather<<<4096, 256, 0, stream>>>(row_start, csr_col, x, dr, out, N);
        k_project<<<2048, 256, 0, stream>>>(W, out, N);
    } else {
        // fallback: round-1 atomic-scatter path (needs only N ints of ws)
        int*   deg = (int*)d_ws;
        float* dr  = (float*)d_ws;
        k_init_deg<<<(N + 255) / 256, 256, 0, stream>>>(deg, N);
        k_count_csr<<<2048, 256, 0, stream>>>(rows, deg, E);  // deg starts at 1
        k_rsqrt<<<(N + 255) / 256, 256, 0, stream>>>(dr, N);
        int n4 = N * (D / 4);
        k_init_out<<<4096, 256, 0, stream>>>((const float4*)x, dr, (float4*)out, n4);
        k_edges<<<4096, 256, 0, stream>>>(rows, cols, x, dr, out, E);
        k_project<<<2048, 256, 0, stream>>>(W, out, N);
    }
}

// Round 3
// 383.852 us; speedup vs baseline: 4.5793x; 1.9616x over previous
//
#include <hip/hip_runtime.h>
#include <hip/hip_bf16.h>

#define D 128  // D_IN == D_OUT == 128

typedef __bf16 bf16x8 __attribute__((ext_vector_type(8)));
typedef float  f32x4  __attribute__((ext_vector_type(4)));

// ===========================================================================
// CSR-build kernels
// ===========================================================================

__global__ __launch_bounds__(256) void k_zero(int* __restrict__ cnt, int n) {
    for (int i = blockIdx.x * blockDim.x + threadIdx.x; i < n; i += gridDim.x * blockDim.x)
        cnt[i] = 0;
}

__global__ __launch_bounds__(256) void k_count_csr(const int* __restrict__ rows,
                                                   int* __restrict__ cnt, int E) {
    for (int e = blockIdx.x * blockDim.x + threadIdx.x; e < E; e += gridDim.x * blockDim.x)
        atomicAdd(&cnt[rows[e]], 1);
}

__global__ __launch_bounds__(256) void k_chunk_sum(const int* __restrict__ cnt,
                                                   int* __restrict__ bsum, int N) {
    __shared__ int sd[256];
    int base = blockIdx.x * 1024;
    int t = threadIdx.x;
    int s = 0;
#pragma unroll
    for (int k = 0; k < 4; ++k) {
        int i = base + t * 4 + k;
        if (i < N) s += cnt[i];
    }
    sd[t] = s;
    __syncthreads();
    for (int off = 128; off > 0; off >>= 1) {
        if (t < off) sd[t] += sd[t + off];
        __syncthreads();
    }
    if (t == 0) bsum[blockIdx.x] = sd[0];
}

__global__ __launch_bounds__(1024) void k_scan_tops(const int* __restrict__ bsum,
                                                    int* __restrict__ boff, int nb,
                                                    int* __restrict__ row_start, int N, int E) {
    __shared__ int sd[1024];
    int t = threadIdx.x;
    int own = (t < nb) ? bsum[t] : 0;
    sd[t] = own;
    __syncthreads();
    for (int off = 1; off < 1024; off <<= 1) {
        int add = (t >= off) ? sd[t - off] : 0;
        __syncthreads();
        sd[t] += add;
        __syncthreads();
    }
    if (t < nb) boff[t] = sd[t] - own;  // exclusive
    if (t == 0) row_start[N] = E;
}

__global__ __launch_bounds__(256) void k_scan_chunk(const int* __restrict__ cnt,
                                                    const int* __restrict__ boff,
                                                    int* __restrict__ row_start,
                                                    int* __restrict__ cursor,
                                                    float* __restrict__ dr, int N) {
    __shared__ int tsum[256];
    int base = blockIdx.x * 1024;
    int t = threadIdx.x;
    int v[4];
    int s = 0;
#pragma unroll
    for (int k = 0; k < 4; ++k) {
        int i = base + t * 4 + k;
        v[k] = (i < N) ? cnt[i] : 0;
        s += v[k];
    }
    tsum[t] = s;
    __syncthreads();
    for (int off = 1; off < 256; off <<= 1) {
        int add = (t >= off) ? tsum[t - off] : 0;
        __syncthreads();
        tsum[t] += add;
        __syncthreads();
    }
    int run = boff[blockIdx.x] + tsum[t] - s;
#pragma unroll
    for (int k = 0; k < 4; ++k) {
        int i = base + t * 4 + k;
        if (i < N) {
            row_start[i] = run;
            cursor[i]    = run;
            dr[i]        = rsqrtf((float)(v[k] + 1));
            run += v[k];
        }
    }
}

__global__ __launch_bounds__(256) void k_scatter(const int* __restrict__ rows,
                                                 const int* __restrict__ cols,
                                                 int* __restrict__ cursor,
                                                 int* __restrict__ csr_col, int E) {
    for (int e = blockIdx.x * blockDim.x + threadIdx.x; e < E; e += gridDim.x * blockDim.x) {
        int p = atomicAdd(&cursor[rows[e]], 1);
        csr_col[p] = cols[e];
    }
}

// ===========================================================================
// gather: out[r] = dr[r]^2 * x[r] + sum_{c in adj(r)} dr[r]*dr[c] * x[c]
// one wave per row; lane covers 2 consecutive floats.
// Col indices + their dr prefetched lane-parallel, broadcast via shfl;
// inner loop unrolled 4x for independent row-gathers in flight.
// ===========================================================================
__global__ __launch_bounds__(256) void k_gather(const int* __restrict__ row_start,
                                                const int* __restrict__ csr_col,
                                                const float* __restrict__ x,
                                                const float* __restrict__ dr,
                                                float* __restrict__ out, int N) {
    int lane = threadIdx.x & 63;
    int gw = (blockIdx.x * blockDim.x + threadIdx.x) >> 6;
    int nw = (gridDim.x * blockDim.x) >> 6;
    for (int r = gw; r < N; r += nw) {
        float drr = dr[r];
        int beg = row_start[r], end = row_start[r + 1];
        const float2 xs = *(const float2*)&x[(size_t)r * D + lane * 2];
        float s = drr * drr;
        float a0 = s * xs.x, a1 = s * xs.y;
        for (int cb = beg; cb < end; cb += 64) {
            int m = end - cb;
            if (m > 64) m = 64;
            int   cidx = (lane < m) ? csr_col[cb + lane] : 0;
            float cdr  = (lane < m) ? dr[cidx] : 0.f;
            int j = 0;
            for (; j + 4 <= m; j += 4) {
                int c0 = __shfl(cidx, j);
                int c1 = __shfl(cidx, j + 1);
                int c2 = __shfl(cidx, j + 2);
                int c3 = __shfl(cidx, j + 3);
                float v0 = drr * __shfl(cdr, j);
                float v1 = drr * __shfl(cdr, j + 1);
                float v2 = drr * __shfl(cdr, j + 2);
                float v3 = drr * __shfl(cdr, j + 3);
                const float2 p0 = *(const float2*)&x[(size_t)c0 * D + lane * 2];
                const float2 p1 = *(const float2*)&x[(size_t)c1 * D + lane * 2];
                const float2 p2 = *(const float2*)&x[(size_t)c2 * D + lane * 2];
                const float2 p3 = *(const float2*)&x[(size_t)c3 * D + lane * 2];
                a0 = fmaf(v0, p0.x, a0); a1 = fmaf(v0, p0.y, a1);
                a0 = fmaf(v1, p1.x, a0); a1 = fmaf(v1, p1.y, a1);
                a0 = fmaf(v2, p2.x, a0); a1 = fmaf(v2, p2.y, a1);
                a0 = fmaf(v3, p3.x, a0); a1 = fmaf(v3, p3.y, a1);
            }
            for (; j < m; ++j) {
                int   c = __shfl(cidx, j);
                float v = drr * __shfl(cdr, j);
                const float2 p = *(const float2*)&x[(size_t)c * D + lane * 2];
                a0 = fmaf(v, p.x, a0);
                a1 = fmaf(v, p.y, a1);
            }
        }
        float2 o;
        o.x = a0;
        o.y = a1;
        *(float2*)&out[(size_t)r * D + lane * 2] = o;
    }
}

// ===========================================================================
// projection + relu via MFMA (bf16 split for fp32 precision), in place.
// out_row = relu(agg_row @ W^T);  out[n][o] = sum_k agg[n][k] * W[o][k]
//
// mfma_f32_16x16x32_bf16: A-frag lane l: row=l&15, k=(l>>4)*8 + 0..7
//                         B-frag lane l: col=l&15, k=(l>>4)*8 + 0..7
//                         C/D: col=lane&15, row=(lane>>4)*4+reg
// B (=W) fragments pre-packed in LDS in fragment order -> lane-linear 16B
// reads, conflict-free. 8 col-tiles x 4 k-steps x 3 split-MFMAs = 96 MFMA
// per 16-row tile per wave.
// ===========================================================================
#define CT 8  // col tiles (128/16)
#define KS 4  // k steps   (128/32)

__global__ __launch_bounds__(256) void k_project_mfma(const float* __restrict__ W,
                                                      float* __restrict__ out, int N) {
    __shared__ bf16x8 Bhi[CT * KS * 64];  // 32 KB
    __shared__ bf16x8 Blo[CT * KS * 64];  // 32 KB

    // stage W fragments (hi/lo split), fragment-order layout
    for (int f = threadIdx.x; f < CT * KS * 64; f += 256) {
        int l  = f & 63;
        int ks = (f >> 6) & 3;
        int ct = f >> 8;
        int o  = ct * 16 + (l & 15);
        int k0 = ks * 32 + ((l >> 4) * 8);
        const float* src = &W[o * D + k0];
        bf16x8 hi, lo;
#pragma unroll
        for (int i = 0; i < 8; ++i) {
            float v  = src[i];
            __bf16 h = (__bf16)v;
            float  r = v - (float)h;
            hi[i] = h;
            lo[i] = (__bf16)r;
        }
        Bhi[f] = hi;
        Blo[f] = lo;
    }
    __syncthreads();

    int lane = threadIdx.x & 63;
    int wib  = threadIdx.x >> 6;
    int gw   = blockIdx.x * 4 + wib;
    int nw   = gridDim.x * 4;
    int nt   = N >> 4;  // 16-row tiles

    int arow  = lane & 15;
    int kbase = (lane >> 4) * 8;

    for (int t = gw; t < nt; t += nw) {
        int row = t * 16 + arow;
        const float* arp = &out[(size_t)row * D + kbase];

        bf16x8 Ahi[KS], Alo[KS];
#pragma unroll
        for (int ks = 0; ks < KS; ++ks) {
            float4 v0 = *(const float4*)&arp[ks * 32];
            float4 v1 = *(const float4*)&arp[ks * 32 + 4];
            float va[8] = {v0.x, v0.y, v0.z, v0.w, v1.x, v1.y, v1.z, v1.w};
            bf16x8 hi, lo;
#pragma unroll
            for (int i = 0; i < 8; ++i) {
                float v  = va[i];
                __bf16 h = (__bf16)v;
                float  r = v - (float)h;
                hi[i] = h;
                lo[i] = (__bf16)r;
            }
            Ahi[ks] = hi;
            Alo[ks] = lo;
        }

        f32x4 acc[CT];
#pragma unroll
        for (int ct = 0; ct < CT; ++ct) acc[ct] = (f32x4){0.f, 0.f, 0.f, 0.f};

#pragma unroll
        for (int ks = 0; ks < KS; ++ks) {
#pragma unroll
            for (int ct = 0; ct < CT; ++ct) {
                bf16x8 bh = Bhi[(ct * KS + ks) * 64 + lane];
                bf16x8 bl = Blo[(ct * KS + ks) * 64 + lane];
                acc[ct] = __builtin_amdgcn_mfma_f32_16x16x32_bf16(Ahi[ks], bh, acc[ct], 0, 0, 0);
                acc[ct] = __builtin_amdgcn_mfma_f32_16x16x32_bf16(Alo[ks], bh, acc[ct], 0, 0, 0);
                acc[ct] = __builtin_amdgcn_mfma_f32_16x16x32_bf16(Ahi[ks], bl, acc[ct], 0, 0, 0);
            }
        }

        int orow = t * 16 + (lane >> 4) * 4;
        int ocol = lane & 15;
#pragma unroll
        for (int ct = 0; ct < CT; ++ct) {
#pragma unroll
            for (int reg = 0; reg < 4; ++reg) {
                out[(size_t)(orow + reg) * D + ct * 16 + ocol] = fmaxf(acc[ct][reg], 0.f);
            }
        }
    }
}

// ===========================================================================
// fallback (atomic path) kernels, used only if ws too small
// ===========================================================================
__global__ __launch_bounds__(256) void k_init_deg(int* __restrict__ deg, int n) {
    for (int i = blockIdx.x * blockDim.x + threadIdx.x; i < n; i += gridDim.x * blockDim.x)
        deg[i] = 1;
}
__global__ __launch_bounds__(256) void k_rsqrt(float* __restrict__ buf, int n) {
    const int* di = (const int*)buf;
    for (int i = blockIdx.x * blockDim.x + threadIdx.x; i < n; i += gridDim.x * blockDim.x) {
        int v = di[i];
        buf[i] = rsqrtf((float)v);
    }
}
__global__ __launch_bounds__(256) void k_init_out(const float4* __restrict__ x4,
                                                  const float* __restrict__ dr,
                                                  float4* __restrict__ out4, int n4) {
    for (int i = blockIdx.x * blockDim.x + threadIdx.x; i < n4; i += gridDim.x * blockDim.x) {
        float d = dr[i >> 5];
        float s = d * d;
        float4 v = x4[i];
        out4[i] = make_float4(v.x * s, v.y * s, v.z * s, v.w * s);
    }
}
__global__ __launch_bounds__(256) void k_edges(const int* __restrict__ rows,
                                               const int* __restrict__ cols,
                                               const float* __restrict__ x,
                                               const float* __restrict__ dr,
                                               float* __restrict__ out, int E) {
    int lane = threadIdx.x & 63;
    int wib  = threadIdx.x >> 6;
    int gw   = blockIdx.x * 4 + wib;
    int nw   = gridDim.x * 4;
    for (int e = gw; e < E; e += nw) {
        int r = rows[e];
        int c = cols[e];
        float val = dr[r] * dr[c];
        const float2 xv = *(const float2*)&x[(size_t)c * D + lane * 2];
        float* po = &out[(size_t)r * D + lane * 2];
        unsafeAtomicAdd(po,     val * xv.x);
        unsafeAtomicAdd(po + 1, val * xv.y);
    }
}

// ===========================================================================
extern "C" void kernel_launch(void* const* d_in, const int* in_sizes, int n_in,
                              void* d_out, int out_size, void* d_ws, size_t ws_size,
                              hipStream_t stream) {
    const float* x   = (const float*)d_in[0];
    const int*   idx = (const int*)d_in[1];
    const float* W   = (const float*)d_in[2];
    float*       out = (float*)d_out;

    int N = in_sizes[0] / D;   // 100000
    int E = in_sizes[1] / 2;   // 1.6M
    const int* rows = idx;
    const int* cols = idx + E;

    int nb = (N + 1023) / 1024;  // scan chunks (98)

    // ws: cnt[N] | row_start[N+1] | cursor[N] | dr[N] (f32) | bsum[nb] | boff[nb] | csr_col[E]
    size_t need = (size_t)(4 * (size_t)N + 1 + 2 * (size_t)nb + (size_t)E) * sizeof(int);

    if (ws_size >= need && nb <= 1024 && (N & 15) == 0) {
        int*   cnt       = (int*)d_ws;
        int*   row_start = cnt + N;
        int*   cursor    = row_start + (N + 1);
        float* dr        = (float*)(cursor + N);
        int*   bsum      = (int*)(dr + N);
        int*   boff      = bsum + nb;
        int*   csr_col   = boff + nb;

        k_zero<<<(N + 255) / 256, 256, 0, stream>>>(cnt, N);
        k_count_csr<<<2048, 256, 0, stream>>>(rows, cnt, E);
        k_chunk_sum<<<nb, 256, 0, stream>>>(cnt, bsum, N);
        k_scan_tops<<<1, 1024, 0, stream>>>(bsum, boff, nb, row_start, N, E);
        k_scan_chunk<<<nb, 256, 0, stream>>>(cnt, boff, row_start, cursor, dr, N);
        k_scatter<<<2048, 256, 0, stream>>>(rows, cols, cursor, csr_col, E);

        k_gather<<<4096, 256, 0, stream>>>(row_start, csr_col, x, dr, out, N);

        int nt = N >> 4;
        int pblocks = (nt + 3) / 4;
        k_project_mfma<<<pblocks, 256, 0, stream>>>(W, out, N);
    } else {
        int*   deg = (int*)d_ws;
        float* dr  = (float*)d_ws;
        k_init_deg<<<(N + 255) / 256, 256, 0, stream>>>(deg, N);
        k_count_csr<<<2048, 256, 0, stream>>>(rows, deg, E);
        k_rsqrt<<<(N + 255) / 256, 256, 0, stream>>>(dr, N);
        int n4 = N * (D / 4);
        k_init_out<<<4096, 256, 0, stream>>>((const float4*)x, dr, (float4*)out, n4);
        k_edges<<<4096, 256, 0, stream>>>(rows, cols, x, dr, out, E);
        // legacy shuffle projection replaced by MFMA path requires ws; reuse
        // atomic-out then MFMA projection (no ws needed by k_project_mfma)
        int nt = N >> 4;
        int pblocks = (nt + 3) / 4;
        k_project_mfma<<<pblocks, 256, 0, stream>>>(W, out, N);
    }
}

// Round 5
// 230.348 us; speedup vs baseline: 7.6310x; 1.6664x over previous
//
#include <hip/hip_runtime.h>
#include <hip/hip_bf16.h>

#define D 128      // D_IN == D_OUT
#define SH 8       // log2 rows per bucket
#define BROWS 256  // rows per bucket
#define NBK_MAX 512
#define CH 8192    // edges per workgroup in k_pairs

typedef __bf16   bf16x8 __attribute__((ext_vector_type(8)));
typedef float    f32x4  __attribute__((ext_vector_type(4)));
typedef _Float16 f16x2  __attribute__((ext_vector_type(2)));
typedef _Float16 f16x4  __attribute__((ext_vector_type(4)));

// ===========================================================================
// generic zero
__global__ __launch_bounds__(256) void k_zero(int* __restrict__ p, int n) {
    for (int i = blockIdx.x * blockDim.x + threadIdx.x; i < n; i += gridDim.x * blockDim.x)
        p[i] = 0;
}

// bucket counts via per-WG LDS histogram
__global__ __launch_bounds__(256) void k_bucket_count(const int* __restrict__ rows,
                                                      int* __restrict__ bcnt, int E, int NBK) {
    __shared__ int h[NBK_MAX];
    for (int i = threadIdx.x; i < NBK; i += 256) h[i] = 0;
    __syncthreads();
    for (int e = blockIdx.x * blockDim.x + threadIdx.x; e < E; e += gridDim.x * blockDim.x)
        atomicAdd(&h[rows[e] >> SH], 1);
    __syncthreads();
    for (int i = threadIdx.x; i < NBK; i += 256) {
        int v = h[i];
        if (v) atomicAdd(&bcnt[i], v);
    }
}

// exclusive scan of bucket counts (NBK <= 512), single block
__global__ __launch_bounds__(512) void k_scan_buckets(const int* __restrict__ bcnt,
                                                      int* __restrict__ boff,
                                                      int* __restrict__ bcur, int NBK, int E) {
    __shared__ int sd[512];
    int t = threadIdx.x;
    int own = (t < NBK) ? bcnt[t] : 0;
    sd[t] = own;
    __syncthreads();
    for (int off = 1; off < 512; off <<= 1) {
        int add = (t >= off) ? sd[t - off] : 0;
        __syncthreads();
        sd[t] += add;
        __syncthreads();
    }
    if (t < NBK) {
        int ex = sd[t] - own;
        boff[t] = ex;
        bcur[t] = ex;
    }
    if (t == 0) boff[NBK] = E;
}

// bucket-partition edges into packed pairs ((r&255)<<24 | c), run-reserved
__global__ __launch_bounds__(256) void k_pairs(const int* __restrict__ rows,
                                               const int* __restrict__ cols,
                                               int* __restrict__ bcur,
                                               unsigned* __restrict__ pairs, int E, int NBK) {
    __shared__ int h[NBK_MAX];
    int e0 = blockIdx.x * CH;
    if (e0 >= E) return;
    int e1 = min(E, e0 + CH);
    for (int i = threadIdx.x; i < NBK; i += 256) h[i] = 0;
    __syncthreads();
    for (int e = e0 + threadIdx.x; e < e1; e += 256)
        atomicAdd(&h[rows[e] >> SH], 1);
    __syncthreads();
    for (int b = threadIdx.x; b < NBK; b += 256) {
        int v = h[b];
        h[b] = v ? atomicAdd(&bcur[b], v) : 0;
    }
    __syncthreads();
    for (int e = e0 + threadIdx.x; e < e1; e += 256) {
        int r = rows[e];
        int b = r >> SH;
        int p = atomicAdd(&h[b], 1);
        pairs[p] = ((unsigned)(r & (BROWS - 1)) << 24) | (unsigned)cols[e];
    }
}

// per-bucket row histogram -> cnt (replaces global atomic count over N)
__global__ __launch_bounds__(256) void k_bucket_hist(const unsigned* __restrict__ pairs,
                                                     const int* __restrict__ boff,
                                                     int* __restrict__ cnt, int N) {
    __shared__ int h[BROWS];
    int b = blockIdx.x;
    int lim = min(N - (b << SH), BROWS);
    h[threadIdx.x] = 0;
    __syncthreads();
    int p0 = boff[b], p1 = boff[b + 1];
    for (int p = p0 + threadIdx.x; p < p1; p += 256)
        atomicAdd(&h[pairs[p] >> 24], 1);
    __syncthreads();
    if (threadIdx.x < lim) cnt[(b << SH) + threadIdx.x] = h[threadIdx.x];
}

// per-1024-chunk sums of cnt
__global__ __launch_bounds__(256) void k_chunk_sum(const int* __restrict__ cnt,
                                                   int* __restrict__ bsum, int N) {
    __shared__ int sd[256];
    int base = blockIdx.x * 1024;
    int t = threadIdx.x;
    int s = 0;
#pragma unroll
    for (int k = 0; k < 4; ++k) {
        int i = base + t * 4 + k;
        if (i < N) s += cnt[i];
    }
    sd[t] = s;
    __syncthreads();
    for (int off = 128; off > 0; off >>= 1) {
        if (t < off) sd[t] += sd[t + off];
        __syncthreads();
    }
    if (t == 0) bsum[blockIdx.x] = sd[0];
}

__global__ __launch_bounds__(1024) void k_scan_tops(const int* __restrict__ bsum,
                                                    int* __restrict__ boff2, int nb,
                                                    int* __restrict__ row_start, int N, int E) {
    __shared__ int sd[1024];
    int t = threadIdx.x;
    int own = (t < nb) ? bsum[t] : 0;
    sd[t] = own;
    __syncthreads();
    for (int off = 1; off < 1024; off <<= 1) {
        int add = (t >= off) ? sd[t - off] : 0;
        __syncthreads();
        sd[t] += add;
        __syncthreads();
    }
    if (t < nb) boff2[t] = sd[t] - own;
    if (t == 0) row_start[N] = E;
}

// per-chunk scan -> row_start; dr = rsqrt(cnt+1)
__global__ __launch_bounds__(256) void k_scan_chunk(const int* __restrict__ cnt,
                                                    const int* __restrict__ boff2,
                                                    int* __restrict__ row_start,
                                                    float* __restrict__ dr, int N) {
    __shared__ int tsum[256];
    int base = blockIdx.x * 1024;
    int t = threadIdx.x;
    int v[4];
    int s = 0;
#pragma unroll
    for (int k = 0; k < 4; ++k) {
        int i = base + t * 4 + k;
        v[k] = (i < N) ? cnt[i] : 0;
        s += v[k];
    }
    tsum[t] = s;
    __syncthreads();
    for (int off = 1; off < 256; off <<= 1) {
        int add = (t >= off) ? tsum[t - off] : 0;
        __syncthreads();
        tsum[t] += add;
        __syncthreads();
    }
    int run = boff2[blockIdx.x] + tsum[t] - s;
#pragma unroll
    for (int k = 0; k < 4; ++k) {
        int i = base + t * 4 + k;
        if (i < N) {
            row_start[i] = run;
            dr[i] = rsqrtf((float)(v[k] + 1));
            run += v[k];
        }
    }
}

// place cols into CSR; cursors in LDS, dest window L2-resident per bucket
__global__ __launch_bounds__(256) void k_place(const unsigned* __restrict__ pairs,
                                               const int* __restrict__ boff,
                                               const int* __restrict__ row_start,
                                               int* __restrict__ csr_col, int N) {
    __shared__ int cur[BROWS];
    int b = blockIdx.x;
    int lim = min(N - (b << SH), BROWS);
    if (threadIdx.x < lim) cur[threadIdx.x] = row_start[(b << SH) + threadIdx.x];
    __syncthreads();
    int p0 = boff[b], p1 = boff[b + 1];
    for (int p = p0 + threadIdx.x; p < p1; p += 256) {
        unsigned v = pairs[p];
        int rl = v >> 24;
        int c  = v & 0xFFFFFF;
        int q = atomicAdd(&cur[rl], 1);
        csr_col[q] = c;
    }
}

// x (fp32) -> xh (fp16)
__global__ __launch_bounds__(256) void k_half(const float4* __restrict__ x4,
                                              f16x4* __restrict__ xh4, int n4) {
    for (int i = blockIdx.x * blockDim.x + threadIdx.x; i < n4; i += gridDim.x * blockDim.x) {
        float4 v = x4[i];
        xh4[i] = (f16x4){(_Float16)v.x, (_Float16)v.y, (_Float16)v.z, (_Float16)v.w};
    }
}

// ===========================================================================
// gather (fp16 x): out[r] = dr[r]^2*x[r] + sum_c dr[r]*dr[c]*x[c]
// ===========================================================================
__global__ __launch_bounds__(256) void k_gather_h(const int* __restrict__ row_start,
                                                  const int* __restrict__ csr_col,
                                                  const _Float16* __restrict__ xh,
                                                  const float* __restrict__ dr,
                                                  float* __restrict__ out, int N) {
    int lane = threadIdx.x & 63;
    int gw = (blockIdx.x * blockDim.x + threadIdx.x) >> 6;
    int nw = (gridDim.x * blockDim.x) >> 6;
    for (int r = gw; r < N; r += nw) {
        float drr = dr[r];
        int beg = row_start[r], end = row_start[r + 1];
        const f16x2 xs = *(const f16x2*)&xh[(size_t)r * D + lane * 2];
        float s = drr * drr;
        float a0 = s * (float)xs[0], a1 = s * (float)xs[1];
        for (int cb = beg; cb < end; cb += 64) {
            int m = end - cb;
            if (m > 64) m = 64;
            int   cidx = (lane < m) ? csr_col[cb + lane] : 0;
            float cdr  = (lane < m) ? dr[cidx] : 0.f;
            int j = 0;
            for (; j + 8 <= m; j += 8) {
#pragma unroll
                for (int u = 0; u < 8; u += 4) {
                    int c0 = __shfl(cidx, j + u);
                    int c1 = __shfl(cidx, j + u + 1);
                    int c2 = __shfl(cidx, j + u + 2);
                    int c3 = __shfl(cidx, j + u + 3);
                    float v0 = drr * __shfl(cdr, j + u);
                    float v1 = drr * __shfl(cdr, j + u + 1);
                    float v2 = drr * __shfl(cdr, j + u + 2);
                    float v3 = drr * __shfl(cdr, j + u + 3);
                    const f16x2 p0 = *(const f16x2*)&xh[(size_t)c0 * D + lane * 2];
                    const f16x2 p1 = *(const f16x2*)&xh[(size_t)c1 * D + lane * 2];
                    const f16x2 p2 = *(const f16x2*)&xh[(size_t)c2 * D + lane * 2];
                    const f16x2 p3 = *(const f16x2*)&xh[(size_t)c3 * D + lane * 2];
                    a0 = fmaf(v0, (float)p0[0], a0); a1 = fmaf(v0, (float)p0[1], a1);
                    a0 = fmaf(v1, (float)p1[0], a0); a1 = fmaf(v1, (float)p1[1], a1);
                    a0 = fmaf(v2, (float)p2[0], a0); a1 = fmaf(v2, (float)p2[1], a1);
                    a0 = fmaf(v3, (float)p3[0], a0); a1 = fmaf(v3, (float)p3[1], a1);
                }
            }
            for (; j < m; ++j) {
                int   c = __shfl(cidx, j);
                float v = drr * __shfl(cdr, j);
                const f16x2 p = *(const f16x2*)&xh[(size_t)c * D + lane * 2];
                a0 = fmaf(v, (float)p[0], a0);
                a1 = fmaf(v, (float)p[1], a1);
            }
        }
        float2 o;
        o.x = a0;
        o.y = a1;
        *(float2*)&out[(size_t)r * D + lane * 2] = o;
    }
}

// fp32 gather (mid-tier fallback if ws can't fit xh)
__global__ __launch_bounds__(256) void k_gather(const int* __restrict__ row_start,
                                                const int* __restrict__ csr_col,
                                                const float* __restrict__ x,
                                                const float* __restrict__ dr,
                                                float* __restrict__ out, int N) {
    int lane = threadIdx.x & 63;
    int gw = (blockIdx.x * blockDim.x + threadIdx.x) >> 6;
    int nw = (gridDim.x * blockDim.x) >> 6;
    for (int r = gw; r < N; r += nw) {
        float drr = dr[r];
        int beg = row_start[r], end = row_start[r + 1];
        const float2 xs = *(const float2*)&x[(size_t)r * D + lane * 2];
        float s = drr * drr;
        float a0 = s * xs.x, a1 = s * xs.y;
        for (int cb = beg; cb < end; cb += 64) {
            int m = end - cb;
            if (m > 64) m = 64;
            int   cidx = (lane < m) ? csr_col[cb + lane] : 0;
            float cdr  = (lane < m) ? dr[cidx] : 0.f;
            int j = 0;
            for (; j + 4 <= m; j += 4) {
                int c0 = __shfl(cidx, j);
                int c1 = __shfl(cidx, j + 1);
                int c2 = __shfl(cidx, j + 2);
                int c3 = __shfl(cidx, j + 3);
                float v0 = drr * __shfl(cdr, j);
                float v1 = drr * __shfl(cdr, j + 1);
                float v2 = drr * __shfl(cdr, j + 2);
                float v3 = drr * __shfl(cdr, j + 3);
                const float2 p0 = *(const float2*)&x[(size_t)c0 * D + lane * 2];
                const float2 p1 = *(const float2*)&x[(size_t)c1 * D + lane * 2];
                const float2 p2 = *(const float2*)&x[(size_t)c2 * D + lane * 2];
                const float2 p3 = *(const float2*)&x[(size_t)c3 * D + lane * 2];
                a0 = fmaf(v0, p0.x, a0); a1 = fmaf(v0, p0.y, a1);
                a0 = fmaf(v1, p1.x, a0); a1 = fmaf(v1, p1.y, a1);
                a0 = fmaf(v2, p2.x, a0); a1 = fmaf(v2, p2.y, a1);
                a0 = fmaf(v3, p3.x, a0); a1 = fmaf(v3, p3.y, a1);
            }
            for (; j < m; ++j) {
                int   c = __shfl(cidx, j);
                float v = drr * __shfl(cdr, j);
                const float2 p = *(const float2*)&x[(size_t)c * D + lane * 2];
                a0 = fmaf(v, p.x, a0);
                a1 = fmaf(v, p.y, a1);
            }
        }
        float2 o;
        o.x = a0;
        o.y = a1;
        *(float2*)&out[(size_t)r * D + lane * 2] = o;
    }
}

// ===========================================================================
// projection + relu via MFMA (bf16 split), in place (proven round 3)
// ===========================================================================
#define CT 8
#define KS 4

__global__ __launch_bounds__(256) void k_project_mfma(const float* __restrict__ W,
                                                      float* __restrict__ out, int N) {
    __shared__ bf16x8 Bhi[CT * KS * 64];
    __shared__ bf16x8 Blo[CT * KS * 64];

    for (int f = threadIdx.x; f < CT * KS * 64; f += 256) {
        int l  = f & 63;
        int ks = (f >> 6) & 3;
        int ct = f >> 8;
        int o  = ct * 16 + (l & 15);
        int k0 = ks * 32 + ((l >> 4) * 8);
        const float* src = &W[o * D + k0];
        bf16x8 hi, lo;
#pragma unroll
        for (int i = 0; i < 8; ++i) {
            float v  = src[i];
            __bf16 h = (__bf16)v;
            float  r = v - (float)h;
            hi[i] = h;
            lo[i] = (__bf16)r;
        }
        Bhi[f] = hi;
        Blo[f] = lo;
    }
    __syncthreads();

    int lane = threadIdx.x & 63;
    int wib  = threadIdx.x >> 6;
    int gw   = blockIdx.x * 4 + wib;
    int nw   = gridDim.x * 4;
    int nt   = N >> 4;

    int arow  = lane & 15;
    int kbase = (lane >> 4) * 8;

    for (int t = gw; t < nt; t += nw) {
        int row = t * 16 + arow;
        const float* arp = &out[(size_t)row * D + kbase];

        bf16x8 Ahi[KS], Alo[KS];
#pragma unroll
        for (int ks = 0; ks < KS; ++ks) {
            float4 v0 = *(const float4*)&arp[ks * 32];
            float4 v1 = *(const float4*)&arp[ks * 32 + 4];
            float va[8] = {v0.x, v0.y, v0.z, v0.w, v1.x, v1.y, v1.z, v1.w};
            bf16x8 hi, lo;
#pragma unroll
            for (int i = 0; i < 8; ++i) {
                float v  = va[i];
                __bf16 h = (__bf16)v;
                float  r = v - (float)h;
                hi[i] = h;
                lo[i] = (__bf16)r;
            }
            Ahi[ks] = hi;
            Alo[ks] = lo;
        }

        f32x4 acc[CT];
#pragma unroll
        for (int ct = 0; ct < CT; ++ct) acc[ct] = (f32x4){0.f, 0.f, 0.f, 0.f};

#pragma unroll
        for (int ks = 0; ks < KS; ++ks) {
#pragma unroll
            for (int ct = 0; ct < CT; ++ct) {
                bf16x8 bh = Bhi[(ct * KS + ks) * 64 + lane];
                bf16x8 bl = Blo[(ct * KS + ks) * 64 + lane];
                acc[ct] = __builtin_amdgcn_mfma_f32_16x16x32_bf16(Ahi[ks], bh, acc[ct], 0, 0, 0);
                acc[ct] = __builtin_amdgcn_mfma_f32_16x16x32_bf16(Alo[ks], bh, acc[ct], 0, 0, 0);
                acc[ct] = __builtin_amdgcn_mfma_f32_16x16x32_bf16(Ahi[ks], bl, acc[ct], 0, 0, 0);
            }
        }

        int orow = t * 16 + (lane >> 4) * 4;
        int ocol = lane & 15;
#pragma unroll
        for (int ct = 0; ct < CT; ++ct) {
#pragma unroll
            for (int reg = 0; reg < 4; ++reg) {
                out[(size_t)(orow + reg) * D + ct * 16 + ocol] = fmaxf(acc[ct][reg], 0.f);
            }
        }
    }
}

// ===========================================================================
// last-resort fallback (round-1 atomic path)
// ===========================================================================
__global__ __launch_bounds__(256) void k_init_deg(int* __restrict__ deg, int n) {
    for (int i = blockIdx.x * blockDim.x + threadIdx.x; i < n; i += gridDim.x * blockDim.x)
        deg[i] = 1;
}
__global__ __launch_bounds__(256) void k_count_atomic(const int* __restrict__ rows,
                                                      int* __restrict__ cnt, int E) {
    for (int e = blockIdx.x * blockDim.x + threadIdx.x; e < E; e += gridDim.x * blockDim.x)
        atomicAdd(&cnt[rows[e]], 1);
}
__global__ __launch_bounds__(256) void k_rsqrt(float* __restrict__ buf, int n) {
    const int* di = (const int*)buf;
    for (int i = blockIdx.x * blockDim.x + threadIdx.x; i < n; i += gridDim.x * blockDim.x) {
        int v = di[i];
        buf[i] = rsqrtf((float)v);
    }
}
__global__ __launch_bounds__(256) void k_init_out(const float4* __restrict__ x4,
                                                  const float* __restrict__ dr,
                                                  float4* __restrict__ out4, int n4) {
    for (int i = blockIdx.x * blockDim.x + threadIdx.x; i < n4; i += gridDim.x * blockDim.x) {
        float d = dr[i >> 5];
        float s = d * d;
        float4 v = x4[i];
        out4[i] = make_float4(v.x * s, v.y * s, v.z * s, v.w * s);
    }
}
__global__ __launch_bounds__(256) void k_edges(const int* __restrict__ rows,
                                               const int* __restrict__ cols,
                                               const float* __restrict__ x,
                                               const float* __restrict__ dr,
                                               float* __restrict__ out, int E) {
    int lane = threadIdx.x & 63;
    int wib  = threadIdx.x >> 6;
    int gw   = blockIdx.x * 4 + wib;
    int nw   = gridDim.x * 4;
    for (int e = gw; e < E; e += nw) {
        int r = rows[e];
        int c = cols[e];
        float val = dr[r] * dr[c];
        const float2 xv = *(const float2*)&x[(size_t)c * D + lane * 2];
        float* po = &out[(size_t)r * D + lane * 2];
        unsafeAtomicAdd(po,     val * xv.x);
        unsafeAtomicAdd(po + 1, val * xv.y);
    }
}

// ===========================================================================
extern "C" void kernel_launch(void* const* d_in, const int* in_sizes, int n_in,
                              void* d_out, int out_size, void* d_ws, size_t ws_size,
                              hipStream_t stream) {
    const float* x   = (const float*)d_in[0];
    const int*   idx = (const int*)d_in[1];
    const float* W   = (const float*)d_in[2];
    float*       out = (float*)d_out;

    int N = in_sizes[0] / D;   // 100000
    int E = in_sizes[1] / 2;   // 1.6M
    const int* rows = idx;
    const int* cols = idx + E;

    int NBK = (N + BROWS - 1) >> SH;   // 391
    int nb  = (N + 1023) / 1024;       // 98

    // workspace layout in 4B words
    size_t off = 0;
    size_t o_pairs = off;  off += (size_t)E;
    size_t o_csr   = off;  off += (size_t)E;
    size_t o_cnt   = off;  off += (size_t)N;
    size_t o_rs    = off;  off += (size_t)N + 1;
    size_t o_dr    = off;  off += (size_t)N;
    size_t o_bsum  = off;  off += (size_t)nb;
    size_t o_boff2 = off;  off += (size_t)nb;
    size_t o_bcnt  = off;  off += (size_t)NBK;
    size_t o_boff  = off;  off += (size_t)NBK + 1;
    size_t o_bcur  = off;  off += (size_t)NBK;
    off = (off + 3) & ~(size_t)3;      // 16B-align xh
    size_t o_xh    = off;  off += ((size_t)N * D) / 2;  // halfs = words/2
    size_t need_full = off * 4;
    size_t need_base = o_xh * 4;

    int* wsw = (int*)d_ws;

    bool shape_ok = (NBK <= NBK_MAX) && (nb <= 1024) && ((N & 15) == 0) && (N < (1 << 24));

    if (shape_ok && ws_size >= need_base) {
        unsigned* pairs     = (unsigned*)(wsw + o_pairs);
        int*      csr_col   = wsw + o_csr;
        int*      cnt       = wsw + o_cnt;
        int*      row_start = wsw + o_rs;
        float*    dr        = (float*)(wsw + o_dr);
        int*      bsum      = wsw + o_bsum;
        int*      boff2     = wsw + o_boff2;
        int*      bcnt      = wsw + o_bcnt;
        int*      boff      = wsw + o_boff;
        int*      bcur      = wsw + o_bcur;
        _Float16* xh        = (_Float16*)(wsw + o_xh);

        // CSR build (bucketed)
        k_zero<<<(NBK + 255) / 256, 256, 0, stream>>>(bcnt, NBK);
        k_bucket_count<<<512, 256, 0, stream>>>(rows, bcnt, E, NBK);
        k_scan_buckets<<<1, 512, 0, stream>>>(bcnt, boff, bcur, NBK, E);
        k_pairs<<<(E + CH - 1) / CH, 256, 0, stream>>>(rows, cols, bcur, pairs, E, NBK);
        k_bucket_hist<<<NBK, 256, 0, stream>>>(pairs, boff, cnt, N);
        k_chunk_sum<<<nb, 256, 0, stream>>>(cnt, bsum, N);
        k_scan_tops<<<1, 1024, 0, stream>>>(bsum, boff2, nb, row_start, N, E);
        k_scan_chunk<<<nb, 256, 0, stream>>>(cnt, boff2, row_start, dr, N);
        k_place<<<NBK, 256, 0, stream>>>(pairs, boff, row_start, csr_col, N);

        // gather + project
        if (ws_size >= need_full) {
            k_half<<<2048, 256, 0, stream>>>((const float4*)x, (f16x4*)xh, N * (D / 4));
            k_gather_h<<<4096, 256, 0, stream>>>(row_start, csr_col, xh, dr, out, N);
        } else {
            k_gather<<<4096, 256, 0, stream>>>(row_start, csr_col, x, dr, out, N);
        }
        int nt = N >> 4;
        k_project_mfma<<<(nt + 3) / 4, 256, 0, stream>>>(W, out, N);
    } else {
        // last-resort atomic path (needs only N words of ws)
        int*   deg = (int*)d_ws;
        float* dr  = (float*)d_ws;
        k_init_deg<<<(N + 255) / 256, 256, 0, stream>>>(deg, N);
        k_count_atomic<<<2048, 256, 0, stream>>>(rows, deg, E);
        k_rsqrt<<<(N + 255) / 256, 256, 0, stream>>>(dr, N);
        int n4 = N * (D / 4);
        k_init_out<<<4096, 256, 0, stream>>>((const float4*)x, dr, (float4*)out, n4);
        k_edges<<<4096, 256, 0, stream>>>(rows, cols, x, dr, out, E);
        int nt = N >> 4;
        k_project_mfma<<<(nt + 3) / 4, 256, 0, stream>>>(W, out, N);
    }
}